// Round 7
// baseline (1153.515 us; speedup 1.0000x reference)
//
#include <hip/hip_runtime.h>

#define N_NODES 100000
#define F 64
#define C 32
#define KH 3
#define E 1600000
#define NE_TOT (KH * E)                 // 4,800,000

#define BKT_SHIFT 7                     // 128 rows per bucket
#define ROWS_PER_BKT 128
#define NB ((N_NODES + ROWS_PER_BKT - 1) / ROWS_PER_BKT)   // 782
#define SEG_SHIFT 15                    // 32768 cols per segment (2 MB bf16 y)
#define NSEG ((N_NODES + (1 << SEG_SHIFT) - 1) >> SEG_SHIFT)  // 4
#define NCB (NSEG * NB)                 // 3128 (seg-major)
#define CHUNK 8192
#define NBIN_BLK ((NE_TOT + CHUNK - 1) / CHUNK)            // 586
#define COL_MASK 0xFFFFF
#define U 8                             // unroll / prefetch batch

typedef unsigned short ushort;
typedef unsigned int uint;

__device__ __forceinline__ float bf2f(ushort u) {
    union { uint i; float f; } v; v.i = ((uint)u) << 16; return v.f;
}
__device__ __forceinline__ ushort f2bf(float f) {
    union { uint i; float f; } v; v.f = f;
    uint u = v.i;
    u += 0x7fffu + ((u >> 16) & 1u);   // RNE
    return (ushort)(u >> 16);
}

// ---------------------------------------------------------------------------
// K1: y[n, c] = sum_f x[n, f] * W[f, c]  (fp32 math, y stored bf16)
// ---------------------------------------------------------------------------
__global__ __launch_bounds__(256) void gemm_xw(const float* __restrict__ x,
                                               const float* __restrict__ W,
                                               ushort* __restrict__ y_h) {
    __shared__ float Ws[F * C];  // 8 KB
    for (int i = threadIdx.x; i < F * C; i += 256) Ws[i] = W[i];
    __syncthreads();

    const int node = blockIdx.x * 256 + threadIdx.x;
    if (node >= N_NODES) return;

    const float4* xp = (const float4*)(x + (size_t)node * F);
    float acc[C];
#pragma unroll
    for (int c = 0; c < C; c++) acc[c] = 0.f;

#pragma unroll
    for (int i = 0; i < 16; i++) {
        float4 v = xp[i];
        const int f = i * 4;
#pragma unroll
        for (int c = 0; c < C; c++) {
            acc[c] += v.x * Ws[(f + 0) * C + c];
            acc[c] += v.y * Ws[(f + 1) * C + c];
            acc[c] += v.z * Ws[(f + 2) * C + c];
            acc[c] += v.w * Ws[(f + 3) * C + c];
        }
    }

    uint pack[16];
#pragma unroll
    for (int i = 0; i < 16; i++)
        pack[i] = (uint)f2bf(acc[2 * i]) | ((uint)f2bf(acc[2 * i + 1]) << 16);
    uint4* yo = (uint4*)(y_h + (size_t)node * C);
#pragma unroll
    for (int i = 0; i < 4; i++)
        yo[i] = make_uint4(pack[4 * i], pack[4 * i + 1], pack[4 * i + 2], pack[4 * i + 3]);
}

// ---------------------------------------------------------------------------
// K2: (seg, bucket) histogram — LDS-aggregated, 3128 bins
// ---------------------------------------------------------------------------
__global__ __launch_bounds__(256) void hist_cb(const int* __restrict__ rows,
                                               const int* __restrict__ cols,
                                               int* __restrict__ cbcnt) {
    __shared__ int h[NCB];   // 12.5 KB
    for (int i = threadIdx.x; i < NCB; i += 256) h[i] = 0;
    __syncthreads();

    const int base = blockIdx.x * CHUNK;
#pragma unroll 4
    for (int j = 0; j < CHUNK / 256; j++) {
        const int e = base + j * 256 + threadIdx.x;
        if (e < NE_TOT)
            atomicAdd(&h[(cols[e] >> SEG_SHIFT) * NB + (rows[e] >> BKT_SHIFT)], 1);
    }
    __syncthreads();
    for (int i = threadIdx.x; i < NCB; i += 256)
        if (h[i]) atomicAdd(&cbcnt[i], h[i]);
}

// ---------------------------------------------------------------------------
// K3: exclusive scan of NCB counts (single block, 4 elems/thread)
// ---------------------------------------------------------------------------
__global__ __launch_bounds__(1024) void scan_cb(const int* __restrict__ cnt,
                                                int* __restrict__ cb_start,
                                                int* __restrict__ cursor) {
    __shared__ int s[1024];
    const int t = threadIdx.x;
    const int base = t * 4;
    int v[4];
    int sum = 0;
#pragma unroll
    for (int u = 0; u < 4; u++) {
        const int idx = base + u;
        v[u] = (idx < NCB) ? cnt[idx] : 0;
        sum += v[u];
    }
    s[t] = sum;
    __syncthreads();
    for (int off = 1; off < 1024; off <<= 1) {
        int a = (t >= off) ? s[t - off] : 0;
        __syncthreads();
        s[t] += a;
        __syncthreads();
    }
    int ex = (t == 0) ? 0 : s[t - 1];
#pragma unroll
    for (int u = 0; u < 4; u++) {
        const int idx = base + u;
        if (idx < NCB) { cb_start[idx] = ex; cursor[idx] = ex; }
        ex += v[u];
    }
    if (t == 1023) cb_start[NCB] = s[1023];
}

// ---------------------------------------------------------------------------
// K4: bin edges by (seg, bucket); record = (rowLocal<<20 | col, w_bits)
// ---------------------------------------------------------------------------
__global__ __launch_bounds__(256) void bin_k(
    const float* __restrict__ vals, const int* __restrict__ rows,
    const int* __restrict__ cols, const float* __restrict__ alpha,
    int* __restrict__ g_cursor, int2* __restrict__ recs) {
    __shared__ int h[NCB];    // 12.5 KB
    __shared__ int cur[NCB];  // 12.5 KB
    for (int i = threadIdx.x; i < NCB; i += 256) h[i] = 0;
    __syncthreads();

    const int base = blockIdx.x * CHUNK;
#pragma unroll 4
    for (int j = 0; j < CHUNK / 256; j++) {
        const int e = base + j * 256 + threadIdx.x;
        if (e < NE_TOT)
            atomicAdd(&h[(cols[e] >> SEG_SHIFT) * NB + (rows[e] >> BKT_SHIFT)], 1);
    }
    __syncthreads();
    for (int i = threadIdx.x; i < NCB; i += 256)
        cur[i] = atomicAdd(&g_cursor[i], h[i]);
    __syncthreads();
#pragma unroll 4
    for (int j = 0; j < CHUNK / 256; j++) {
        const int e = base + j * 256 + threadIdx.x;
        if (e >= NE_TOT) continue;
        const int row = rows[e];
        const int col = cols[e];
        const int cb = (col >> SEG_SHIFT) * NB + (row >> BKT_SHIFT);
        const int k = (e >= 2 * E) ? 2 : (e >= E) ? 1 : 0;
        const float w = vals[e] * alpha[k];
        const int slot = atomicAdd(&cur[cb], 1);
        const int packed = col | ((row & (ROWS_PER_BKT - 1)) << 20);
        recs[slot] = make_int2(packed, __float_as_int(w));
    }
}

// ---------------------------------------------------------------------------
// K5 v4: one block per (seg, bucket) — seg-major order so all CUs work the
// same 2 MB y-segment concurrently (XCD-L2-resident gathers). 128x32 fp32
// tile in LDS; 8 groups of 32 lanes over contiguous record runs; U-batch
// prefetch; global-atomic flush (bias seeded by seg 0).
// ---------------------------------------------------------------------------
__global__ __launch_bounds__(256) void acc_k(
    const int* __restrict__ cb_start, const int2* __restrict__ recs,
    const ushort* __restrict__ y_h, const float* __restrict__ bias,
    float* __restrict__ out) {
    __shared__ float accs[ROWS_PER_BKT * C];  // 16 KB
    const int tid = threadIdx.x;
    const int bx = blockIdx.x;            // = seg * NB + bucket
    const int seg = bx / NB;
    const int b = bx - seg * NB;

    if (seg == 0) {
        for (int i = tid; i < ROWS_PER_BKT * C; i += 256) accs[i] = bias[i & (C - 1)];
    } else {
        for (int i = tid; i < ROWS_PER_BKT * C; i += 256) accs[i] = 0.f;
    }
    __syncthreads();

    const int bs = cb_start[bx];
    const int be = cb_start[bx + 1];

    const int grp = tid >> 5;   // 8 groups of 32 lanes
    const int c = tid & 31;
    const int glen = be - bs;
    int i = bs + (glen * grp) / 8;
    const int ge = bs + (glen * (grp + 1)) / 8;

    if (i + U <= ge) {
        int2 r[U];
#pragma unroll
        for (int u = 0; u < U; u++) r[u] = recs[i + u];

        while (i + 2 * U <= ge) {
            float p[U];
#pragma unroll
            for (int u = 0; u < U; u++)
                p[u] = bf2f(y_h[((size_t)(r[u].x & COL_MASK) << 5) + c]);
            int2 rn[U];
#pragma unroll
            for (int u = 0; u < U; u++) rn[u] = recs[i + U + u];
#pragma unroll
            for (int u = 0; u < U; u++)
                atomicAdd(&accs[(r[u].x >> 20) * C + c], __int_as_float(r[u].y) * p[u]);
#pragma unroll
            for (int u = 0; u < U; u++) r[u] = rn[u];
            i += U;
        }
        {
            float p[U];
#pragma unroll
            for (int u = 0; u < U; u++)
                p[u] = bf2f(y_h[((size_t)(r[u].x & COL_MASK) << 5) + c]);
#pragma unroll
            for (int u = 0; u < U; u++)
                atomicAdd(&accs[(r[u].x >> 20) * C + c], __int_as_float(r[u].y) * p[u]);
            i += U;
        }
    }
    for (; i < ge; i++) {
        const int2 r0 = recs[i];
        const float p0 = bf2f(y_h[((size_t)(r0.x & COL_MASK) << 5) + c]);
        atomicAdd(&accs[(r0.x >> 20) * C + c], __int_as_float(r0.y) * p0);
    }
    __syncthreads();

    const int row0 = b << BKT_SHIFT;
    const int nrows = min(ROWS_PER_BKT, N_NODES - row0);
    for (int idx = tid; idx < nrows * C; idx += 256)
        unsafeAtomicAdd(&out[(size_t)row0 * C + idx], accs[idx]);
}

// ---------------------------------------------------------------------------
extern "C" void kernel_launch(void* const* d_in, const int* in_sizes, int n_in,
                              void* d_out, int out_size, void* d_ws, size_t ws_size,
                              hipStream_t stream) {
    const float* x         = (const float*)d_in[0];
    const float* edge_vals = (const float*)d_in[1];
    const float* W         = (const float*)d_in[2];
    const float* b         = (const float*)d_in[3];
    const float* alpha     = (const float*)d_in[4];
    const int*   edge_rows = (const int*)d_in[5];
    const int*   edge_cols = (const int*)d_in[6];
    float*       out       = (float*)d_out;          // [N, C] fp32

    // ws layout (4 B units) — ~45 MB total (52.4 MB proven safe)
    int* wsi = (int*)d_ws;
    ushort* y_h     = (ushort*)wsi;                  // 3.2M bf16 (6.4 MB) = 1.6M ints
    int*  cbcnt     = wsi + 1600000;                 // NCB (pad 4096)
    int*  cb_start  = wsi + 1604096;                 // NCB+1 (pad 4096)
    int*  g_cursor  = wsi + 1608192;                 // NCB (pad 4096)
    int2* recs      = (int2*)(wsi + 1612288);        // 4.8M int2 (38.4 MB)

    hipMemsetAsync(cbcnt, 0, NCB * sizeof(int), stream);
    hipMemsetAsync(out, 0, (size_t)N_NODES * C * sizeof(float), stream);

    gemm_xw<<<(N_NODES + 255) / 256, 256, 0, stream>>>(x, W, y_h);

    hist_cb<<<NBIN_BLK, 256, 0, stream>>>(edge_rows, edge_cols, cbcnt);
    scan_cb<<<1, 1024, 0, stream>>>(cbcnt, cb_start, g_cursor);
    bin_k<<<NBIN_BLK, 256, 0, stream>>>(edge_vals, edge_rows, edge_cols, alpha,
                                        g_cursor, recs);
    acc_k<<<NCB, 256, 0, stream>>>(cb_start, recs, y_h, b, out);
}